// Round 1
// 499.159 us; speedup vs baseline: 1.0700x; 1.0700x over previous
//
#include <hip/hip_runtime.h>
#include <hip/hip_bf16.h>

#define B 4
#define N 2048
#define D 2048
#define H 16
#define DH 128
#define NT 32  // N / 64 key tiles

typedef unsigned short u16;
typedef __attribute__((ext_vector_type(8))) short short8;   // 8 bf16 in 4 VGPRs
typedef __attribute__((ext_vector_type(4))) float floatx4;  // MFMA C/D frag

__device__ __forceinline__ u16 f2b(float f) {
    union { __hip_bfloat16 h; u16 u; } cv;
    cv.h = __float2bfloat16(f);
    return cv.u;
}

__device__ __forceinline__ floatx4 mfma16(short8 a, short8 b, floatx4 c) {
    return __builtin_amdgcn_mfma_f32_16x16x32_bf16(a, b, c, 0, 0, 0);
}

#if __has_builtin(__builtin_amdgcn_exp2f)
#define EXP2(x) __builtin_amdgcn_exp2f(x)
#else
#define EXP2(x) exp2f(x)
#endif

// async global->LDS, 16B per lane; LDS dest = wave-uniform base + lane*16
__device__ __forceinline__ void async16(const void* g, void* l) {
    __builtin_amdgcn_global_load_lds(
        (const __attribute__((address_space(1))) unsigned int*)g,
        (__attribute__((address_space(3))) unsigned int*)l, 16, 0, 0);
}

// ---------------------------------------------------------------- cvt_x
__global__ __launch_bounds__(256) void cvt_x(const float* __restrict__ x,
                                             u16* __restrict__ xb) {
    size_t i = ((size_t)blockIdx.x * 256 + threadIdx.x) * 8;
    float4 v0 = *(const float4*)&x[i];
    float4 v1 = *(const float4*)&x[i + 4];
    union { u16 u[8]; uint4 s; } pk;
    pk.u[0] = f2b(v0.x); pk.u[1] = f2b(v0.y); pk.u[2] = f2b(v0.z); pk.u[3] = f2b(v0.w);
    pk.u[4] = f2b(v1.x); pk.u[5] = f2b(v1.y); pk.u[6] = f2b(v1.z); pk.u[7] = f2b(v1.w);
    *(uint4*)&xb[i] = pk.s;
}

// ---------------------------------------------------------------- cvt_w_t
// W fp32 [k][n] -> Wt bf16 [z][n][k].
// Wq folds log2(e)/sqrt(128) so softmax uses raw exp2.
__global__ __launch_bounds__(256) void cvt_w_t(const float* __restrict__ Wq,
                                               const float* __restrict__ Wk,
                                               const float* __restrict__ Wv,
                                               u16* __restrict__ wt) {
    __shared__ float tile[64][65];
    const int z = blockIdx.z;
    const float* W = (z == 0) ? Wq : (z == 1) ? Wk : Wv;
    const float scl = (z == 0) ? 0.12751743342f : 1.0f;  // log2e/sqrt(128)
    const int k0 = blockIdx.x * 64, n0 = blockIdx.y * 64;
    const int tr = threadIdx.x >> 4, tc = threadIdx.x & 15;
#pragma unroll
    for (int i = 0; i < 4; i++) {
        int kk = tr + 16 * i;
        float4 vv = *(const float4*)&W[(size_t)(k0 + kk) * D + n0 + tc * 4];
        tile[kk][tc * 4 + 0] = vv.x; tile[kk][tc * 4 + 1] = vv.y;
        tile[kk][tc * 4 + 2] = vv.z; tile[kk][tc * 4 + 3] = vv.w;
    }
    __syncthreads();
#pragma unroll
    for (int i = 0; i < 4; i++) {
        int nn = tr + 16 * i;
        union { u16 u[4]; ushort4 s; } pk;
#pragma unroll
        for (int j = 0; j < 4; j++) pk.u[j] = f2b(tile[tc * 4 + j][nn] * scl);
        *(ushort4*)&wt[(size_t)z * D * D + (size_t)(n0 + nn) * D + k0 + tc * 4] = pk.s;
    }
}

// ---------------------------------------------------------------- qkv_gemm
// 256x256 tile, BK=64, 8 waves (2M x 4N), 8-phase schedule (T2+T3+T4+T5).
// LDS: 2 dbuf x {A,B} x 2 half-tiles [128][64] bf16 = 128 KiB, 1 block/CU.
// Staging: global_load_lds w16, linear LDS dest, source pre-swizzled so the
// 16B slot s of row r holds logical slot s^(r&7); reads apply the same XOR
// -> fragment ds_read_b128 is bank-conflict-free (2 lanes/bank).
// Per K-tile, 4 phases; per phase: {ds_read subtile || stage 1 half-tile} ->
// barrier -> lgkmcnt(0) -> setprio(1) -> 16 MFMA -> setprio(0) -> barrier.
// Counted vmcnt(4) once per K-tile BEFORE the closing barrier (per-wave wait
// + barrier => all waves' staged halves landed); drains to 0 only at g==30.
#define KT 32          // K / BK = 2048/64
__global__ __launch_bounds__(512, 2) void qkv_gemm(const u16* __restrict__ xb,
                                                   const u16* __restrict__ wt,
                                                   u16* __restrict__ qo,
                                                   u16* __restrict__ ko,
                                                   u16* __restrict__ vo) {
    __shared__ u16 lds[2][2][2][128 * 64];  // [dbuf][A=0/B=1][half][row*64+col]

    // XCD-aware bijective swizzle: 768 blocks, 768 % 8 == 0
    const int bid = blockIdx.x;
    const int swz = (bid & 7) * 96 + (bid >> 3);
    const int tm = swz & 31;   // M tile 0..31
    const int tn = swz >> 5;   // N tile 0..23 (consecutive swz share tn -> B panel in L2)

    const int t = threadIdx.x, lane = t & 63, w = t >> 6;
    const int wr = w >> 2, wc = w & 3;        // wave grid 2(M) x 4(N)
    const int q4 = lane >> 4, lr = lane & 15; // frag quad-row / row

    const int m0 = tm * 256;
    const int n0 = tn * 256;

    // per-thread pre-swizzled staging source offsets (elements)
    unsigned aoff[2][2], boff[2][2];  // [half][issue]
#pragma unroll
    for (int i = 0; i < 2; i++) {
        const int off = i * 8192 + w * 1024 + lane * 16;  // linear byte in half-tile
        const int row = off >> 7;          // 0..127
        const int s = (off >> 4) & 7;      // 16B slot 0..7
        const int col = ((s ^ (row & 7))) * 8;
#pragma unroll
        for (int h = 0; h < 2; h++) {
            aoff[h][i] = (unsigned)((m0 + h * 128 + row) * D + col);
            boff[h][i] = (unsigned)((n0 + h * 128 + row) * D + col);
        }
    }

#define STAGE_A(buf, h, j) {                                                        \
    async16(xb + aoff[h][0] + (unsigned)(j) * 64, (char*)&lds[buf][0][h][0] + w * 1024);        \
    async16(xb + aoff[h][1] + (unsigned)(j) * 64, (char*)&lds[buf][0][h][0] + 8192 + w * 1024); }
#define STAGE_B(buf, h, j) {                                                        \
    async16(wt + boff[h][0] + (unsigned)(j) * 64, (char*)&lds[buf][1][h][0] + w * 1024);        \
    async16(wt + boff[h][1] + (unsigned)(j) * 64, (char*)&lds[buf][1][h][0] + 8192 + w * 1024); }
#define BAR() __builtin_amdgcn_s_barrier()
#define LGKM0() asm volatile("s_waitcnt lgkmcnt(0)" ::: "memory")

    floatx4 acc[8][4];
#pragma unroll
    for (int i = 0; i < 8; i++)
#pragma unroll
        for (int j = 0; j < 4; j++) acc[i][j] = (floatx4){0.f, 0.f, 0.f, 0.f};

    // ---- prologue: K-tile 0 fully + A of K-tile 1 (6 half-tiles, 12 loads)
    STAGE_A(0, 0, 0); STAGE_A(0, 1, 0);
    STAGE_B(0, 0, 0); STAGE_B(0, 1, 0);
    STAGE_A(1, 0, 1); STAGE_A(1, 1, 1);
    asm volatile("s_waitcnt vmcnt(4)" ::: "memory");  // K-tile 0 landed; A(1) in flight
    BAR();

    for (int g = 0; g < KT; g++) {
        const int cur = g & 1, nxt = cur ^ 1;
        short8 a0[4][2], a1[4][2], b0[2][2], b1[2][2];

        // ================= phase 0: ds A-mq0(8) + B-nq0(4); stage B.h0(g+1)
#pragma unroll
        for (int mf = 0; mf < 4; mf++) {
            const int hrow = mf * 16 + lr;
            const int sw = hrow & 7;
#pragma unroll
            for (int ks = 0; ks < 2; ks++)
                a0[mf][ks] = *(const short8*)&lds[cur][0][wr][hrow * 64 + ((ks * 4 + q4) ^ sw) * 8];
        }
#pragma unroll
        for (int nf = 0; nf < 2; nf++) {
            const int hrow = (wc & 1) * 64 + nf * 16 + lr;
            const int sw = hrow & 7;
#pragma unroll
            for (int ks = 0; ks < 2; ks++)
                b0[nf][ks] = *(const short8*)&lds[cur][1][wc >> 1][hrow * 64 + ((ks * 4 + q4) ^ sw) * 8];
        }
        if (g + 1 < KT) STAGE_B(nxt, 0, g + 1);
        BAR();
        LGKM0();
        __builtin_amdgcn_s_setprio(1);
#pragma unroll
        for (int nf = 0; nf < 2; nf++)
#pragma unroll
            for (int mf = 0; mf < 4; mf++)
#pragma unroll
                for (int ks = 0; ks < 2; ks++)
                    acc[mf][nf] = mfma16(a0[mf][ks], b0[nf][ks], acc[mf][nf]);
        __builtin_amdgcn_s_setprio(0);
        BAR();

        // ================= phase 1: ds A-mq1(8); stage B.h1(g+1)
#pragma unroll
        for (int mf = 0; mf < 4; mf++) {
            const int hrow = 64 + mf * 16 + lr;
            const int sw = hrow & 7;
#pragma unroll
            for (int ks = 0; ks < 2; ks++)
                a1[mf][ks] = *(const short8*)&lds[cur][0][wr][hrow * 64 + ((ks * 4 + q4) ^ sw) * 8];
        }
        if (g + 1 < KT) STAGE_B(nxt, 1, g + 1);
        BAR();
        LGKM0();
        __builtin_amdgcn_s_setprio(1);
#pragma unroll
        for (int nf = 0; nf < 2; nf++)
#pragma unroll
            for (int mf = 0; mf < 4; mf++)
#pragma unroll
                for (int ks = 0; ks < 2; ks++)
                    acc[4 + mf][nf] = mfma16(a1[mf][ks], b0[nf][ks], acc[4 + mf][nf]);
        __builtin_amdgcn_s_setprio(0);
        BAR();

        // ================= phase 2: ds B-nq1(4); stage A.h0(g+2) (A halves of
        // cur are fully consumed after phase 1's closing barrier)
#pragma unroll
        for (int nf = 0; nf < 2; nf++) {
            const int hrow = (wc & 1) * 64 + (2 + nf) * 16 + lr;
            const int sw = hrow & 7;
#pragma unroll
            for (int ks = 0; ks < 2; ks++)
                b1[nf][ks] = *(const short8*)&lds[cur][1][wc >> 1][hrow * 64 + ((ks * 4 + q4) ^ sw) * 8];
        }
        if (g + 2 < KT) STAGE_A(cur, 0, g + 2);
        BAR();
        LGKM0();
        __builtin_amdgcn_s_setprio(1);
#pragma unroll
        for (int nf = 0; nf < 2; nf++)
#pragma unroll
            for (int mf = 0; mf < 4; mf++)
#pragma unroll
                for (int ks = 0; ks < 2; ks++)
                    acc[4 + mf][2 + nf] = mfma16(a1[mf][ks], b1[nf][ks], acc[4 + mf][2 + nf]);
        __builtin_amdgcn_s_setprio(0);
        BAR();

        // ================= phase 3: stage A.h1(g+2); MFMA (mq0,nq1)
        if (g + 2 < KT) STAGE_A(cur, 1, g + 2);
        BAR();
        __builtin_amdgcn_s_setprio(1);
#pragma unroll
        for (int nf = 0; nf < 2; nf++)
#pragma unroll
            for (int mf = 0; mf < 4; mf++)
#pragma unroll
                for (int ks = 0; ks < 2; ks++)
                    acc[mf][2 + nf] = mfma16(a0[mf][ks], b1[nf][ks], acc[mf][2 + nf]);
        __builtin_amdgcn_s_setprio(0);
        // K-tile boundary: per-wave counted wait, THEN barrier => all waves'
        // B(g+1) (and older) landed; A(g+2)'s 4 loads stay in flight.
        if (g == KT - 2) { asm volatile("s_waitcnt vmcnt(0)" ::: "memory"); }
        else if (g < KT - 2) { asm volatile("s_waitcnt vmcnt(4)" ::: "memory"); }
        BAR();
    }

    // ---- epilogue: scatter C (block is entirely within one z)
    const int z = tn >> 3;
    u16* dst = (z == 0) ? qo : (z == 1) ? ko : vo;
    const int c2b = (tn & 7) * 256 + wc * 64;
    const int grb = tm * 256 + wr * 128;
#pragma unroll
    for (int mf = 0; mf < 8; mf++)
#pragma unroll
        for (int nf = 0; nf < 4; nf++)
#pragma unroll
            for (int r = 0; r < 4; r++) {
                int gr = grb + mf * 16 + q4 * 4 + r;
                int c2 = c2b + nf * 16 + lr;
                int b_ = gr >> 11, n_ = gr & (N - 1);
                int head = c2 >> 7, dcol = c2 & 127;
                dst[((size_t)(b_ * H + head) * N + n_) * DH + dcol] = f2b(acc[mf][nf][r]);
            }
#undef STAGE_A
#undef STAGE_B
#undef BAR
#undef LGKM0
}

// ---------------------------------------------------------------- transpose_v
// V bf16 [bh][n][dd] -> Vt bf16 [bh][dd][n], keys kappa-permuted within each
// 64-block. NEW kappa (matches 2x2-split S writer): position kp holds key
//   key = 32*(kp>>5) + 16*(kp&1) + ((kp>>1)&15)
// (i.e. kappa = 32a + 2*l + t for key = 32a + 16t + l). PV sums over keys,
// so a consistent permutation of P and V is transparent.
__global__ __launch_bounds__(256) void transpose_v(const u16* __restrict__ v,
                                                   u16* __restrict__ vt) {
    __shared__ u16 tile[64][72];
    const int bh = blockIdx.z;
    const int n0 = blockIdx.x * 64, d0 = blockIdx.y * 64;
    const int t = threadIdx.x;
#pragma unroll
    for (int i = 0; i < 2; i++) {
        int gid = t + 256 * i;
        int nl = gid >> 3, g = gid & 7;
        *(uint4*)&tile[nl][g * 8] =
            *(const uint4*)&v[((size_t)bh * N + n0 + nl) * DH + d0 + g * 8];
    }
    __syncthreads();
#pragma unroll
    for (int i = 0; i < 2; i++) {
        int gid = t + 256 * i;
        int dl = gid >> 3, gn = gid & 7;
        union { u16 u[8]; uint4 s; } pk;
#pragma unroll
        for (int j = 0; j < 8; j++) {
            int kp = gn * 8 + j;
            int src = 32 * (kp >> 5) + 16 * (kp & 1) + ((kp >> 1) & 15);
            pk.u[j] = tile[src][dl];
        }
        *(uint4*)&vt[((size_t)bh * DH + d0 + dl) * N + n0 + gn * 8] = pk.s;
    }
}

// ---------------------------------------------------------------- attn
// Flash attention, BQ=128, BK=64, 4 waves in a 2x2 split:
//   wave(a,b), a=w&1, b=w>>1.
//   S phase : rows [64b,64b+64) x keys [32a,32a+32)  (K reads halved, reuse 4)
//   PV phase: rows [64b,64b+64) x dd   [64a,64a+64)  (V reads halved)
// P is cross-wave -> barrier B between S and PV; prefetch for the next tile
// is issued AFTER barrier B so no barrier ever drains an in-flight prefetch
// (barrier A's drain target was issued a full PV phase earlier).
// Fixed-offset softmax in exp2 domain: p = exp2(s' - 17.3123).
#define FMAX2 17.312340491f   // 12 * log2(e)
__global__ __launch_bounds__(256, 2) void attn_kernel(const u16* __restrict__ q,
                                                      const u16* __restrict__ k,
                                                      const u16* __restrict__ vt,
                                                      float* __restrict__ out) {
    __shared__ u16 Ks[2][64][128];    // 32 KB, granule swizzle g^=(row&15)
    __shared__ u16 Vts[2][128][64];   // 32 KB (kappa keys), g^=(row&7)
    __shared__ u16 Ps[128][64];       // 16 KB bf16 kappa; 4B-unit u^=((row&7)<<2)
                                      // total 81920 B -> 2 blocks/CU

    const int beta = blockIdx.x;                  // 0..1023
    const int bh = (beta & 7) + 8 * (beta >> 7);  // one head's q-tiles -> one XCD
    const int qt = (beta >> 3) & 15;
    const int t = threadIdx.x;
    const int w = t >> 6, lane = t & 63;
    const int half = lane >> 4, lr = lane & 15;
    const int a = w & 1, b = w >> 1;

    // Q fragments for 64 rows/wave, straight from global (one-time)
    const size_t qbase = ((size_t)bh * N + (size_t)qt * 128) * DH;
    short8 af[4][4];
#pragma unroll
    for (int rt = 0; rt < 4; rt++)
#pragma unroll
        for (int ks = 0; ks < 4; ks++)
            af[rt][ks] = *(const short8*)&q[qbase + (size_t)(64 * b + 16 * rt + lr) * DH
                                            + ks * 32 + half * 8];

    float lrow[4][4];
    floatx4 o[4][4];
#pragma unroll
    for (int rt = 0; rt < 4; rt++)
#pragma unroll
        for (int r = 0; r < 4; r++) lrow[rt][r] = 0.f;
#pragma unroll
    for (int rt = 0; rt < 4; rt++)
#pragma unroll
        for (int ct = 0; ct < 4; ct++) o[rt][ct] = (floatx4){0.f, 0.f, 0.f, 0.f};

    // per-lane staging source pointers (swizzle hoisted)
    const size_t kbase = (size_t)bh * N * DH;
    const size_t vtbase = (size_t)bh * DH * N;
    const u16* kp[4];
    const u16* vp[4];
#pragma unroll
    for (int c = 0; c < 4; c++) {
        int grp = 4 * w + c;
        int krow = 4 * grp + (lane >> 4);
        int kg = (lane & 15) ^ (krow & 15);
        kp[c] = &k[kbase + (size_t)krow * DH + kg * 8];
        int vrow = 8 * grp + (lane >> 3);
        int vg = (lane & 7) ^ (vrow & 7);
        vp[c] = &vt[vtbase + (size_t)vrow * N + vg * 8];
    }

    // prologue: stage tile 0 into buffer 0
#pragma unroll
    for (int c = 0; c < 4; c++) {
        async16(kp[c], (char*)&Ks[0][0][0] + (4 * w + c) * 1024);
        async16(vp[c], (char*)&Vts[0][0][0] + (4 * w + c) * 1024);
    }

    for (int kt = 0; kt < NT; kt++) {
        const int cur = kt & 1;
        __syncthreads();  // barrier A: drains prefetch issued a full PV ago

        // ---- S = Q K^T : rows [64b,+64) x keys [32a,+32)
        floatx4 sf[4][2];
#pragma unroll
        for (int ct = 0; ct < 2; ct++) {
            short8 bf[4];
#pragma unroll
            for (int ks = 0; ks < 4; ks++) {
                int gs = (4 * ks + half) ^ lr;
                bf[ks] = *(const short8*)&Ks[cur][32 * a + 16 * ct + lr][gs * 8];
            }
#pragma unroll
            for (int rt = 0; rt < 4; rt++) {
                floatx4 s = (floatx4){0.f, 0.f, 0.f, 0.f};
#pragma unroll
                for (int ks = 0; ks < 4; ks++) s = mfma16(af[rt][ks], bf[ks], s);
                sf[rt][ct] = s;
            }
        }

        // ---- softmax (fixed offset, exp2) + P write (b32, kappa pair)
#pragma unroll
        for (int rt = 0; rt < 4; rt++)
#pragma unroll
            for (int r = 0; r < 4; r++) {
                int row = 64 * b + 16 * rt + 4 * half + r;
                float p0 = EXP2(sf[rt][0][r] - FMAX2);
                float p1 = EXP2(sf[rt][1][r] - FMAX2);
                lrow[rt][r] += p0 + p1;
                unsigned int pw = (unsigned int)f2b(p0) | ((unsigned int)f2b(p1) << 16);
                int u = (16 * a + lr) ^ ((row & 7) << 2);   // 4B-unit swizzle
                *(unsigned int*)&Ps[row][u * 2] = pw;       // kappa = 32a+2lr+{0,1}
            }

        __syncthreads();  // barrier B: P visible (no vmem outstanding here)

        // ---- prefetch next tile (issued after barrier B: stays in flight
        //      through PV and is only drained at next iter's barrier A)
        if (kt + 1 < NT) {
            const int nb = cur ^ 1;
#pragma unroll
            for (int c = 0; c < 4; c++) {
                async16(kp[c] + (size_t)(kt + 1) * 64 * DH,
                        (char*)&Ks[nb][0][0] + (4 * w + c) * 1024);
                async16(vp[c] + (size_t)(kt + 1) * 64,
                        (char*)&Vts[nb][0][0] + (4 * w + c) * 1024);
            }
        }

        // ---- O += P @ V : rows [64b,+64) x dd [64a,+64), all 64 keys
#pragma unroll
        for (int ks = 0; ks < 2; ks++) {
            short8 a2[4];
#pragma unroll
            for (int rt = 0; rt < 4; rt++) {
                int g = (4 * ks + half) ^ (lr & 7);
                a2[rt] = *(const short8*)&Ps[64 * b + 16 * rt + lr][g * 8];
            }
#pragma unroll
            for (int ct = 0; ct < 4; ct++) {
                int dd = 64 * a + 16 * ct + lr;
                int gv = (4 * ks + half) ^ (lr & 7);
                short8 bv = *(const short8*)&Vts[cur][dd][gv * 8];
#pragma unroll
                for (int rt = 0; rt < 4; rt++)
                    o[rt][ct] = mfma16(a2[rt], bv, o[rt][ct]);
            }
        }
    }

    // ---- epilogue: cross-wave row-sum (each wave holds a 32-key partial)
    __syncthreads();                      // all PV reads of Ps done
    float* Ls = (float*)&Ps[0][0];        // [2][128] partial sums, aliases Ps
#pragma unroll
    for (int rt = 0; rt < 4; rt++)
#pragma unroll
        for (int r = 0; r < 4; r++) {
            float s = lrow[rt][r];
            s += __shfl_xor(s, 1);
            s += __shfl_xor(s, 2);
            s += __shfl_xor(s, 4);
            s += __shfl_xor(s, 8);
            if (lr == 0) Ls[a * 128 + (64 * b + 16 * rt + 4 * half + r)] = s;
        }
    __syncthreads();
    const size_t obase = ((size_t)bh * N + (size_t)qt * 128) * DH;
#pragma unroll
    for (int rt = 0; rt < 4; rt++)
#pragma unroll
        for (int r = 0; r < 4; r++) {
            int row = 64 * b + 16 * rt + 4 * half + r;
            float inv = 1.f / (Ls[row] + Ls[128 + row]);
#pragma unroll
            for (int ct = 0; ct < 4; ct++)
                out[obase + (size_t)row * DH + 64 * a + 16 * ct + lr] = o[rt][ct][r] * inv;
        }
}

// ---------------------------------------------------------------- launch
extern "C" void kernel_launch(void* const* d_in, const int* in_sizes, int n_in,
                              void* d_out, int out_size, void* d_ws, size_t ws_size,
                              hipStream_t stream) {
    const float* x  = (const float*)d_in[0];
    const float* Wq = (const float*)d_in[1];
    const float* Wk = (const float*)d_in[2];
    const float* Wv = (const float*)d_in[3];
    float* out = (float*)d_out;
    char* ws = (char*)d_ws;

    u16* xb = (u16*)(ws);                  // 32 MB  bf16 X
    u16* wt = (u16*)(ws + 33554432);       // 24 MB  bf16 W^T x3 (Wq scaled)
    u16* qb = (u16*)(ws + 58720256);       // 32 MB  Q bf16 [bh][n][d]
    u16* kb = (u16*)(ws + 92274688);       // 32 MB  K bf16 [bh][n][d]
    u16* vb = (u16*)(ws + 125829120);      // 32 MB  V bf16 [bh][n][d]
    u16* vtb = (u16*)(ws);                 // 32 MB  V^T kappa [bh][d][n]

    cvt_x<<<dim3(8192), dim3(256), 0, stream>>>(x, xb);
    cvt_w_t<<<dim3(32, 32, 3), dim3(256), 0, stream>>>(Wq, Wk, Wv, wt);
    qkv_gemm<<<dim3(768), dim3(512), 0, stream>>>(xb, wt, qb, kb, vb);
    transpose_v<<<dim3(32, 2, 64), dim3(256), 0, stream>>>(vb, vtb);
    attn_kernel<<<dim3(1024), dim3(256), 0, stream>>>(qb, kb, vtb, out);
}

// Round 3
// 487.207 us; speedup vs baseline: 1.0962x; 1.0245x over previous
//
#include <hip/hip_runtime.h>
#include <hip/hip_bf16.h>

#define B 4
#define N 2048
#define D 2048
#define H 16
#define DH 128
#define NT 32  // N / 64 key tiles

typedef unsigned short u16;
typedef __attribute__((ext_vector_type(8))) short short8;   // 8 bf16 in 4 VGPRs
typedef __attribute__((ext_vector_type(4))) float floatx4;  // MFMA C/D frag

__device__ __forceinline__ u16 f2b(float f) {
    union { __hip_bfloat16 h; u16 u; } cv;
    cv.h = __float2bfloat16(f);
    return cv.u;
}

__device__ __forceinline__ floatx4 mfma16(short8 a, short8 b, floatx4 c) {
    return __builtin_amdgcn_mfma_f32_16x16x32_bf16(a, b, c, 0, 0, 0);
}

#if __has_builtin(__builtin_amdgcn_exp2f)
#define EXP2(x) __builtin_amdgcn_exp2f(x)
#else
#define EXP2(x) exp2f(x)
#endif

// async global->LDS, 16B per lane; LDS dest = wave-uniform base + lane*16
__device__ __forceinline__ void async16(const void* g, void* l) {
    __builtin_amdgcn_global_load_lds(
        (const __attribute__((address_space(1))) unsigned int*)g,
        (__attribute__((address_space(3))) unsigned int*)l, 16, 0, 0);
}

// ---------------------------------------------------------------- cvt_x
__global__ __launch_bounds__(256) void cvt_x(const float* __restrict__ x,
                                             u16* __restrict__ xb) {
    size_t i = ((size_t)blockIdx.x * 256 + threadIdx.x) * 8;
    float4 v0 = *(const float4*)&x[i];
    float4 v1 = *(const float4*)&x[i + 4];
    union { u16 u[8]; uint4 s; } pk;
    pk.u[0] = f2b(v0.x); pk.u[1] = f2b(v0.y); pk.u[2] = f2b(v0.z); pk.u[3] = f2b(v0.w);
    pk.u[4] = f2b(v1.x); pk.u[5] = f2b(v1.y); pk.u[6] = f2b(v1.z); pk.u[7] = f2b(v1.w);
    *(uint4*)&xb[i] = pk.s;
}

// ---------------------------------------------------------------- cvt_w_t
// W fp32 [k][n] -> Wt bf16 [z][n][k].
// Wq folds log2(e)/sqrt(128) so softmax uses raw exp2.
__global__ __launch_bounds__(256) void cvt_w_t(const float* __restrict__ Wq,
                                               const float* __restrict__ Wk,
                                               const float* __restrict__ Wv,
                                               u16* __restrict__ wt) {
    __shared__ float tile[64][65];
    const int z = blockIdx.z;
    const float* W = (z == 0) ? Wq : (z == 1) ? Wk : Wv;
    const float scl = (z == 0) ? 0.12751743342f : 1.0f;  // log2e/sqrt(128)
    const int k0 = blockIdx.x * 64, n0 = blockIdx.y * 64;
    const int tr = threadIdx.x >> 4, tc = threadIdx.x & 15;
#pragma unroll
    for (int i = 0; i < 4; i++) {
        int kk = tr + 16 * i;
        float4 vv = *(const float4*)&W[(size_t)(k0 + kk) * D + n0 + tc * 4];
        tile[kk][tc * 4 + 0] = vv.x; tile[kk][tc * 4 + 1] = vv.y;
        tile[kk][tc * 4 + 2] = vv.z; tile[kk][tc * 4 + 3] = vv.w;
    }
    __syncthreads();
#pragma unroll
    for (int i = 0; i < 4; i++) {
        int nn = tr + 16 * i;
        union { u16 u[4]; ushort4 s; } pk;
#pragma unroll
        for (int j = 0; j < 4; j++) pk.u[j] = f2b(tile[tc * 4 + j][nn] * scl);
        *(ushort4*)&wt[(size_t)z * D * D + (size_t)(n0 + nn) * D + k0 + tc * 4] = pk.s;
    }
}

// ---------------------------------------------------------------- qkv_gemm
// 256x256 tile, BK=64, 8 waves (2M x 4N). v2 schedule: all 24 ds_read_b128
// issued at tile top (compiler emits fine-grained counted lgkmcnt under the
// first MFMA clusters -> LDS stream overlaps MFMA instead of serializing),
// 2 barriers per K-tile, counted vmcnt(4) (drain-0 only at g==KT-2).
//   entry BAR (buffer cur fully valid; A(g+1) 4 loads in flight)
//   stage B(g+1)->lds[nxt][1]           (4 loads)
//   issue a0,b0,a1,b1 reads (24)        (from lds[cur])
//   MFMA a0b0 (16), MFMA a1b0 (16)      (a-reads all consumed here)
//   BAR1  -> all waves' a-reads done -> safe to overwrite A[cur]
//   stage A(g+2)->lds[cur][0]           (4 loads)
//   MFMA a1b1 (16), MFMA a0b1 (16)      (b1 consumed before closing BAR)
//   vmcnt(4) [A(g+1),B(g+1) landed; A(g+2) stays in flight]; BAR2
// WAR audit: A[cur] overwrite after BAR1 (reads consumed pre-BAR1);
// B[nxt] write never aliases cur reads; b1 consumed before B(g+2) overwrite.
// XCD swizzle: bijective 16(tm) x 6(tn) rectangle per XCD -> concurrent
// working set ~12 MB (was 33 MB: whole A per XCD).
#define KT 32          // K / BK = 2048/64
__global__ __launch_bounds__(512, 2) void qkv_gemm(const u16* __restrict__ xb,
                                                   const u16* __restrict__ wt,
                                                   u16* __restrict__ qo,
                                                   u16* __restrict__ ko,
                                                   u16* __restrict__ vo) {
    __shared__ u16 lds[2][2][2][128 * 64];  // [dbuf][A=0/B=1][half][row*64+col]

    // XCD-aware bijective swizzle: XCD c gets a 16x6 tile rectangle.
    const int bid = blockIdx.x;
    const int c = bid & 7, i = bid >> 3;        // XCD, idx 0..95
    const int i6 = (i * 43) >> 8;               // i/6 exact for 0..95
    const int tm = ((c >> 2) << 4) + i6;        // 0..31
    const int tn = (c & 3) * 6 + (i - 6 * i6);  // 0..23

    const int t = threadIdx.x, lane = t & 63, w = t >> 6;
    const int wr = w >> 2, wc = w & 3;        // wave grid 2(M) x 4(N)
    const int q4 = lane >> 4, lr = lane & 15; // frag quad-row / row

    const int m0 = tm * 256;
    const int n0 = tn * 256;

    // per-thread pre-swizzled staging source offsets (elements)
    unsigned aoff[2][2], boff[2][2];  // [half][issue]
#pragma unroll
    for (int ii = 0; ii < 2; ii++) {
        const int off = ii * 8192 + w * 1024 + lane * 16;  // linear byte in half-tile
        const int row = off >> 7;          // 0..127
        const int s = (off >> 4) & 7;      // 16B slot 0..7
        const int col = ((s ^ (row & 7))) * 8;
#pragma unroll
        for (int h = 0; h < 2; h++) {
            aoff[h][ii] = (unsigned)((m0 + h * 128 + row) * D + col);
            boff[h][ii] = (unsigned)((n0 + h * 128 + row) * D + col);
        }
    }

#define STAGE_A(buf, h, j) {                                                        \
    async16(xb + aoff[h][0] + (unsigned)(j) * 64, (char*)&lds[buf][0][h][0] + w * 1024);        \
    async16(xb + aoff[h][1] + (unsigned)(j) * 64, (char*)&lds[buf][0][h][0] + 8192 + w * 1024); }
#define STAGE_B(buf, h, j) {                                                        \
    async16(wt + boff[h][0] + (unsigned)(j) * 64, (char*)&lds[buf][1][h][0] + w * 1024);        \
    async16(wt + boff[h][1] + (unsigned)(j) * 64, (char*)&lds[buf][1][h][0] + 8192 + w * 1024); }
#define BAR() __builtin_amdgcn_s_barrier()

    floatx4 acc[8][4];
#pragma unroll
    for (int x = 0; x < 8; x++)
#pragma unroll
        for (int j = 0; j < 4; j++) acc[x][j] = (floatx4){0.f, 0.f, 0.f, 0.f};

    // ---- prologue: K-tile 0 fully + A of K-tile 1 (6 half-tiles, 12 loads/thread)
    STAGE_A(0, 0, 0); STAGE_A(0, 1, 0);
    STAGE_B(0, 0, 0); STAGE_B(0, 1, 0);
    STAGE_A(1, 0, 1); STAGE_A(1, 1, 1);
    asm volatile("s_waitcnt vmcnt(4)" ::: "memory");  // K-tile 0 landed; A(1) in flight
    BAR();

    for (int g = 0; g < KT; g++) {
        const int cur = g & 1, nxt = cur ^ 1;

        // ---- stage B(g+1) first (vmem issue early, latency hides under MFMA)
        if (g + 1 < KT) { STAGE_B(nxt, 0, g + 1); STAGE_B(nxt, 1, g + 1); }

        // ---- issue ALL fragment reads for this K-tile (compiler streams them
        //      with counted lgkmcnt under the MFMA clusters below)
        short8 a0[4][2], a1[4][2], b0[2][2], b1[2][2];
#pragma unroll
        for (int mf = 0; mf < 4; mf++) {
            const int hrow = mf * 16 + lr;
            const int sw = hrow & 7;
#pragma unroll
            for (int ks = 0; ks < 2; ks++)
                a0[mf][ks] = *(const short8*)&lds[cur][0][wr][hrow * 64 + ((ks * 4 + q4) ^ sw) * 8];
        }
#pragma unroll
        for (int nf = 0; nf < 2; nf++) {
            const int hrow = (wc & 1) * 64 + nf * 16 + lr;
            const int sw = hrow & 7;
#pragma unroll
            for (int ks = 0; ks < 2; ks++)
                b0[nf][ks] = *(const short8*)&lds[cur][1][wc >> 1][hrow * 64 + ((ks * 4 + q4) ^ sw) * 8];
        }
#pragma unroll
        for (int mf = 0; mf < 4; mf++) {
            const int hrow = 64 + mf * 16 + lr;
            const int sw = hrow & 7;
#pragma unroll
            for (int ks = 0; ks < 2; ks++)
                a1[mf][ks] = *(const short8*)&lds[cur][0][wr][hrow * 64 + ((ks * 4 + q4) ^ sw) * 8];
        }
#pragma unroll
        for (int nf = 0; nf < 2; nf++) {
            const int hrow = (wc & 1) * 64 + (2 + nf) * 16 + lr;
            const int sw = hrow & 7;
#pragma unroll
            for (int ks = 0; ks < 2; ks++)
                b1[nf][ks] = *(const short8*)&lds[cur][1][wc >> 1][hrow * 64 + ((ks * 4 + q4) ^ sw) * 8];
        }

        // ---- cluster 1: a0 x b0
        __builtin_amdgcn_s_setprio(1);
#pragma unroll
        for (int nf = 0; nf < 2; nf++)
#pragma unroll
            for (int mf = 0; mf < 4; mf++)
#pragma unroll
                for (int ks = 0; ks < 2; ks++)
                    acc[mf][nf] = mfma16(a0[mf][ks], b0[nf][ks], acc[mf][nf]);
        __builtin_amdgcn_s_setprio(0);

        // ---- cluster 2: a1 x b0 (all a-reads consumed after this)
        __builtin_amdgcn_s_setprio(1);
#pragma unroll
        for (int nf = 0; nf < 2; nf++)
#pragma unroll
            for (int mf = 0; mf < 4; mf++)
#pragma unroll
                for (int ks = 0; ks < 2; ks++)
                    acc[4 + mf][nf] = mfma16(a1[mf][ks], b0[nf][ks], acc[4 + mf][nf]);
        __builtin_amdgcn_s_setprio(0);

        BAR();  // barrier 1: every wave's a-reads done -> A[cur] may be overwritten

        // ---- stage A(g+2) into the just-freed A[cur]
        if (g + 2 < KT) { STAGE_A(cur, 0, g + 2); STAGE_A(cur, 1, g + 2); }

        // ---- clusters 3+4: a1 x b1, a0 x b1
        __builtin_amdgcn_s_setprio(1);
#pragma unroll
        for (int nf = 0; nf < 2; nf++)
#pragma unroll
            for (int mf = 0; mf < 4; mf++)
#pragma unroll
                for (int ks = 0; ks < 2; ks++)
                    acc[4 + mf][2 + nf] = mfma16(a1[mf][ks], b1[nf][ks], acc[4 + mf][2 + nf]);
#pragma unroll
        for (int nf = 0; nf < 2; nf++)
#pragma unroll
            for (int mf = 0; mf < 4; mf++)
#pragma unroll
                for (int ks = 0; ks < 2; ks++)
                    acc[mf][2 + nf] = mfma16(a0[mf][ks], b1[nf][ks], acc[mf][2 + nf]);
        __builtin_amdgcn_s_setprio(0);

        // ---- K-tile boundary: per-wave counted wait + barrier publishes
        //      A(g+1),B(g+1); A(g+2)'s 4 loads stay in flight.
        if (g == KT - 2) { asm volatile("s_waitcnt vmcnt(0)" ::: "memory"); }
        else if (g < KT - 2) { asm volatile("s_waitcnt vmcnt(4)" ::: "memory"); }
        if (g + 1 < KT) BAR();  // barrier 2 (closing)
    }

    // ---- epilogue: scatter C (block is entirely within one z)
    const int z = tn >> 3;
    u16* dst = (z == 0) ? qo : (z == 1) ? ko : vo;
    const int c2b = (tn & 7) * 256 + wc * 64;
    const int grb = tm * 256 + wr * 128;
#pragma unroll
    for (int mf = 0; mf < 8; mf++)
#pragma unroll
        for (int nf = 0; nf < 4; nf++)
#pragma unroll
            for (int r = 0; r < 4; r++) {
                int gr = grb + mf * 16 + q4 * 4 + r;
                int c2 = c2b + nf * 16 + lr;
                int b_ = gr >> 11, n_ = gr & (N - 1);
                int head = c2 >> 7, dcol = c2 & 127;
                dst[((size_t)(b_ * H + head) * N + n_) * DH + dcol] = f2b(acc[mf][nf][r]);
            }
#undef STAGE_A
#undef STAGE_B
#undef BAR
}

// ---------------------------------------------------------------- transpose_v
// V bf16 [bh][n][dd] -> Vt bf16 [bh][dd][n], keys kappa-permuted within each
// 64-block. NEW kappa (matches 2x2-split S writer): position kp holds key
//   key = 32*(kp>>5) + 16*(kp&1) + ((kp>>1)&15)
// (i.e. kappa = 32a + 2*l + t for key = 32a + 16t + l). PV sums over keys,
// so a consistent permutation of P and V is transparent.
__global__ __launch_bounds__(256) void transpose_v(const u16* __restrict__ v,
                                                   u16* __restrict__ vt) {
    __shared__ u16 tile[64][72];
    const int bh = blockIdx.z;
    const int n0 = blockIdx.x * 64, d0 = blockIdx.y * 64;
    const int t = threadIdx.x;
#pragma unroll
    for (int i = 0; i < 2; i++) {
        int gid = t + 256 * i;
        int nl = gid >> 3, g = gid & 7;
        *(uint4*)&tile[nl][g * 8] =
            *(const uint4*)&v[((size_t)bh * N + n0 + nl) * DH + d0 + g * 8];
    }
    __syncthreads();
#pragma unroll
    for (int i = 0; i < 2; i++) {
        int gid = t + 256 * i;
        int dl = gid >> 3, gn = gid & 7;
        union { u16 u[8]; uint4 s; } pk;
#pragma unroll
        for (int j = 0; j < 8; j++) {
            int kp = gn * 8 + j;
            int src = 32 * (kp >> 5) + 16 * (kp & 1) + ((kp >> 1) & 15);
            pk.u[j] = tile[src][dl];
        }
        *(uint4*)&vt[((size_t)bh * DH + d0 + dl) * N + n0 + gn * 8] = pk.s;
    }
}

// ---------------------------------------------------------------- attn
// Flash attention, BQ=128, BK=64, 4 waves in a 2x2 split:
//   wave(a,b), a=w&1, b=w>>1.
//   S phase : rows [64b,64b+64) x keys [32a,32a+32)  (K reads halved, reuse 4)
//   PV phase: rows [64b,64b+64) x dd   [64a,64a+64)  (V reads halved)
// P is cross-wave -> barrier B between S and PV; prefetch for the next tile
// is issued AFTER barrier B so no barrier ever drains an in-flight prefetch
// (barrier A's drain target was issued a full PV phase earlier).
// Fixed-offset softmax in exp2 domain: p = exp2(s' - 17.3123).
#define FMAX2 17.312340491f   // 12 * log2(e)
__global__ __launch_bounds__(256, 2) void attn_kernel(const u16* __restrict__ q,
                                                      const u16* __restrict__ k,
                                                      const u16* __restrict__ vt,
                                                      float* __restrict__ out) {
    __shared__ u16 Ks[2][64][128];    // 32 KB, granule swizzle g^=(row&15)
    __shared__ u16 Vts[2][128][64];   // 32 KB (kappa keys), g^=(row&7)
    __shared__ u16 Ps[128][64];       // 16 KB bf16 kappa; 4B-unit u^=((row&7)<<2)
                                      // total 81920 B -> 2 blocks/CU

    const int beta = blockIdx.x;                  // 0..1023
    const int bh = (beta & 7) + 8 * (beta >> 7);  // one head's q-tiles -> one XCD
    const int qt = (beta >> 3) & 15;
    const int t = threadIdx.x;
    const int w = t >> 6, lane = t & 63;
    const int half = lane >> 4, lr = lane & 15;
    const int a = w & 1, b = w >> 1;

    // Q fragments for 64 rows/wave, straight from global (one-time)
    const size_t qbase = ((size_t)bh * N + (size_t)qt * 128) * DH;
    short8 af[4][4];
#pragma unroll
    for (int rt = 0; rt < 4; rt++)
#pragma unroll
        for (int ks = 0; ks < 4; ks++)
            af[rt][ks] = *(const short8*)&q[qbase + (size_t)(64 * b + 16 * rt + lr) * DH
                                            + ks * 32 + half * 8];

    float lrow[4][4];
    floatx4 o[4][4];
#pragma unroll
    for (int rt = 0; rt < 4; rt++)
#pragma unroll
        for (int r = 0; r < 4; r++) lrow[rt][r] = 0.f;
#pragma unroll
    for (int rt = 0; rt < 4; rt++)
#pragma unroll
        for (int ct = 0; ct < 4; ct++) o[rt][ct] = (floatx4){0.f, 0.f, 0.f, 0.f};

    // per-lane staging source pointers (swizzle hoisted)
    const size_t kbase = (size_t)bh * N * DH;
    const size_t vtbase = (size_t)bh * DH * N;
    const u16* kp[4];
    const u16* vp[4];
#pragma unroll
    for (int c = 0; c < 4; c++) {
        int grp = 4 * w + c;
        int krow = 4 * grp + (lane >> 4);
        int kg = (lane & 15) ^ (krow & 15);
        kp[c] = &k[kbase + (size_t)krow * DH + kg * 8];
        int vrow = 8 * grp + (lane >> 3);
        int vg = (lane & 7) ^ (vrow & 7);
        vp[c] = &vt[vtbase + (size_t)vrow * N + vg * 8];
    }

    // prologue: stage tile 0 into buffer 0
#pragma unroll
    for (int c = 0; c < 4; c++) {
        async16(kp[c], (char*)&Ks[0][0][0] + (4 * w + c) * 1024);
        async16(vp[c], (char*)&Vts[0][0][0] + (4 * w + c) * 1024);
    }

    for (int kt = 0; kt < NT; kt++) {
        const int cur = kt & 1;
        __syncthreads();  // barrier A: drains prefetch issued a full PV ago

        // ---- S = Q K^T : rows [64b,+64) x keys [32a,+32)
        floatx4 sf[4][2];
#pragma unroll
        for (int ct = 0; ct < 2; ct++) {
            short8 bf[4];
#pragma unroll
            for (int ks = 0; ks < 4; ks++) {
                int gs = (4 * ks + half) ^ lr;
                bf[ks] = *(const short8*)&Ks[cur][32 * a + 16 * ct + lr][gs * 8];
            }
#pragma unroll
            for (int rt = 0; rt < 4; rt++) {
                floatx4 s = (floatx4){0.f, 0.f, 0.f, 0.f};
#pragma unroll
                for (int ks = 0; ks < 4; ks++) s = mfma16(af[rt][ks], bf[ks], s);
                sf[rt][ct] = s;
            }
        }

        // ---- softmax (fixed offset, exp2) + P write (b32, kappa pair)
#pragma unroll
        for (int rt = 0; rt < 4; rt++)
#pragma unroll
            for (int r = 0; r < 4; r++) {
                int row = 64 * b + 16 * rt + 4 * half + r;
                float p0 = EXP2(sf[rt][0][r] - FMAX2);
                float p1 = EXP2(sf[rt][1][r] - FMAX2);
                lrow[rt][r] += p0 + p1;
                unsigned int pw = (unsigned int)f2b(p0) | ((unsigned int)f2b(p1) << 16);
                int u = (16 * a + lr) ^ ((row & 7) << 2);   // 4B-unit swizzle
                *(unsigned int*)&Ps[row][u * 2] = pw;       // kappa = 32a+2lr+{0,1}
            }

        __syncthreads();  // barrier B: P visible (no vmem outstanding here)

        // ---- prefetch next tile (issued after barrier B: stays in flight
        //      through PV and is only drained at next iter's barrier A)
        if (kt + 1 < NT) {
            const int nb = cur ^ 1;
#pragma unroll
            for (int c = 0; c < 4; c++) {
                async16(kp[c] + (size_t)(kt + 1) * 64 * DH,
                        (char*)&Ks[nb][0][0] + (4 * w + c) * 1024);
                async16(vp[c] + (size_t)(kt + 1) * 64,
                        (char*)&Vts[nb][0][0] + (4 * w + c) * 1024);
            }
        }

        // ---- O += P @ V : rows [64b,+64) x dd [64a,+64), all 64 keys
#pragma unroll
        for (int ks = 0; ks < 2; ks++) {
            short8 a2[4];
#pragma unroll
            for (int rt = 0; rt < 4; rt++) {
                int g = (4 * ks + half) ^ (lr & 7);
                a2[rt] = *(const short8*)&Ps[64 * b + 16 * rt + lr][g * 8];
            }
#pragma unroll
            for (int ct = 0; ct < 4; ct++) {
                int dd = 64 * a + 16 * ct + lr;
                int gv = (4 * ks + half) ^ (lr & 7);
                short8 bv = *(const short8*)&Vts[cur][dd][gv * 8];
#pragma unroll
                for (int rt = 0; rt < 4; rt++)
                    o[rt][ct] = mfma16(a2[rt], bv, o[rt][ct]);
            }
        }
    }

    // ---- epilogue: cross-wave row-sum (each wave holds a 32-key partial)
    __syncthreads();                      // all PV reads of Ps done
    float* Ls = (float*)&Ps[0][0];        // [2][128] partial sums, aliases Ps
#pragma unroll
    for (int rt = 0; rt < 4; rt++)
#pragma unroll
        for (int r = 0; r < 4; r++) {
            float s = lrow[rt][r];
            s += __shfl_xor(s, 1);
            s += __shfl_xor(s, 2);
            s += __shfl_xor(s, 4);
            s += __shfl_xor(s, 8);
            if (lr == 0) Ls[a * 128 + (64 * b + 16 * rt + 4 * half + r)] = s;
        }
    __syncthreads();
    const size_t obase = ((size_t)bh * N + (size_t)qt * 128) * DH;
#pragma unroll
    for (int rt = 0; rt < 4; rt++)
#pragma unroll
        for (int r = 0; r < 4; r++) {
            int row = 64 * b + 16 * rt + 4 * half + r;
            float inv = 1.f / (Ls[row] + Ls[128 + row]);
#pragma unroll
            for (int ct = 0; ct < 4; ct++)
                out[obase + (size_t)row * DH + 64 * a + 16 * ct + lr] = o[rt][ct][r] * inv;
        }
}

// ---------------------------------------------------------------- launch
extern "C" void kernel_launch(void* const* d_in, const int* in_sizes, int n_in,
                              void* d_out, int out_size, void* d_ws, size_t ws_size,
                              hipStream_t stream) {
    const float* x  = (const float*)d_in[0];
    const float* Wq = (const float*)d_in[1];
    const float* Wk = (const float*)d_in[2];
    const float* Wv = (const float*)d_in[3];
    float* out = (float*)d_out;
    char* ws = (char*)d_ws;

    u16* xb = (u16*)(ws);                  // 32 MB  bf16 X
    u16* wt = (u16*)(ws + 33554432);       // 24 MB  bf16 W^T x3 (Wq scaled)
    u16* qb = (u16*)(ws + 58720256);       // 32 MB  Q bf16 [bh][n][d]
    u16* kb = (u16*)(ws + 92274688);       // 32 MB  K bf16 [bh][n][d]
    u16* vb = (u16*)(ws + 125829120);      // 32 MB  V bf16 [bh][n][d]
    u16* vtb = (u16*)(ws);                 // 32 MB  V^T kappa [bh][d][n]

    cvt_x<<<dim3(8192), dim3(256), 0, stream>>>(x, xb);
    cvt_w_t<<<dim3(32, 32, 3), dim3(256), 0, stream>>>(Wq, Wk, Wv, wt);
    qkv_gemm<<<dim3(768), dim3(512), 0, stream>>>(xb, wt, qb, kb, vb);
    transpose_v<<<dim3(32, 2, 64), dim3(256), 0, stream>>>(vb, vtb);
    attn_kernel<<<dim3(1024), dim3(256), 0, stream>>>(qb, kb, vtb, out);
}